// Round 2
// 327.203 us; speedup vs baseline: 1.0253x; 1.0253x over previous
//
#include <hip/hip_runtime.h>

typedef unsigned short ushort_t;
typedef __attribute__((ext_vector_type(8))) short bf16x8;     // 8 bf16 (4 VGPRs)
typedef __attribute__((ext_vector_type(4))) float f32x4;
typedef __attribute__((ext_vector_type(4))) unsigned short us4;

#define DM 2048
#define RK 64

__device__ __forceinline__ ushort_t f2b(float f) {
    union { float f; unsigned u; } x; x.f = f;
    unsigned r = x.u + 0x7fff + ((x.u >> 16) & 1);   // RNE
    return (ushort_t)(r >> 16);
}

// ---------------- P1: Mmid[64][64] = butterfly(Wbs) @ Wcr ----------------
// Butterfly applied directly to Wbs rows (O(N log N)), no Bf materialization.
// 16 blocks each redundantly compute T1 in LDS, then 256 Mmid entries each.
__global__ void k_p1(const float* __restrict__ Wbs, const float* __restrict__ Af,
                     const float* __restrict__ Wcr, float* __restrict__ Mmid) {
    __shared__ float X[64 * 256];          // 64 KB, becomes T1
    const int tid = threadIdx.x;

    // load Wbs (16384 floats) coalesced, float4
#pragma unroll
    for (int i = 0; i < 16; ++i) {
        int e = (i * 256 + tid) * 4;
        *(float4*)&X[e] = *(const float4*)&Wbs[e];
    }
    __syncthreads();

    // 8 butterfly levels, MSB-first (level l acts on bit 7-l), x' = x @ A[l]
#pragma unroll
    for (int l = 0; l < 8; ++l) {
        const int bit = 1 << (7 - l);
        const float a00 = Af[l * 4 + 0], a01 = Af[l * 4 + 1];
        const float a10 = Af[l * 4 + 2], a11 = Af[l * 4 + 3];
#pragma unroll 4
        for (int p = 0; p < 32; ++p) {     // 8192 disjoint pairs / 256 threads
            int pid = p * 256 + tid;
            int row = pid >> 7;
            int off = pid & 127;
            int lo = off & (bit - 1);
            int n0 = ((off ^ lo) << 1) | lo;
            int n1 = n0 | bit;
            float x0 = X[row * 256 + n0], x1 = X[row * 256 + n1];
            X[row * 256 + n0] = x0 * a00 + x1 * a10;
            X[row * 256 + n1] = x0 * a01 + x1 * a11;
        }
        __syncthreads();
    }

    // Mmid[r1][r2] = sum_n T1[r1][n] * Wcr[n][r2]  (one entry per thread)
    int g = blockIdx.x * 256 + tid;        // 0..4095
    int r1 = g >> 6, r2 = g & 63;
    float s = 0.f;
#pragma unroll 8
    for (int n = 0; n < 256; ++n) s += X[r1 * 256 + n] * Wcr[n * 64 + r2];
    Mmid[g] = s;
}

// ---------------- P2: WeffT[64][2048] = (Wbr @ Mmid)^T, WcT[2048][64] = Wcm^T ----
__global__ void k_p2(const float* __restrict__ Wbr, const float* __restrict__ Mmid,
                     const float* __restrict__ Wcm,
                     ushort_t* __restrict__ WeffT, ushort_t* __restrict__ WcT) {
    const int b = blockIdx.x, tid = threadIdx.x;
    if (b < 32) {
        // WeffT tile: k-range [b*64, b*64+64), all 64 n
        __shared__ float LW[64][65];       // Wbr[k0+kk][r], padded
        __shared__ float LM[64 * 64];      // Mmid
#pragma unroll
        for (int i = 0; i < 4; ++i) {      // Wbr tile = 16 KB contiguous
            int e = (i * 256 + tid) * 4;
            int kk = e >> 6, r = e & 63;
            float4 v = *(const float4*)&Wbr[(size_t)b * 4096 + e];
            LW[kk][r] = v.x; LW[kk][r + 1] = v.y; LW[kk][r + 2] = v.z; LW[kk][r + 3] = v.w;
        }
#pragma unroll
        for (int i = 0; i < 4; ++i) {
            int e = (i * 256 + tid) * 4;
            *(float4*)&LM[e] = *(const float4*)&Mmid[e];
        }
        __syncthreads();

        int kk = tid & 63, n0 = (tid >> 6) * 16;
        float acc[16];
#pragma unroll
        for (int j = 0; j < 16; ++j) acc[j] = 0.f;
        for (int r = 0; r < 64; ++r) {
            float wv = LW[kk][r];
            const float* mrow = &LM[r * 64 + n0];
            float4 m0 = *(const float4*)(mrow);
            float4 m1 = *(const float4*)(mrow + 4);
            float4 m2 = *(const float4*)(mrow + 8);
            float4 m3 = *(const float4*)(mrow + 12);
            acc[0] += wv * m0.x; acc[1] += wv * m0.y; acc[2] += wv * m0.z; acc[3] += wv * m0.w;
            acc[4] += wv * m1.x; acc[5] += wv * m1.y; acc[6] += wv * m1.z; acc[7] += wv * m1.w;
            acc[8] += wv * m2.x; acc[9] += wv * m2.y; acc[10] += wv * m2.z; acc[11] += wv * m2.w;
            acc[12] += wv * m3.x; acc[13] += wv * m3.y; acc[14] += wv * m3.z; acc[15] += wv * m3.w;
        }
#pragma unroll
        for (int j = 0; j < 16; ++j)
            WeffT[(size_t)(n0 + j) * DM + b * 64 + kk] = f2b(acc[j]);
    } else {
        // WcT transpose tile: n-range [(b-32)*64, +64)
        __shared__ float LT[64][65];
        const int n0 = (b - 32) * 64;
#pragma unroll
        for (int i = 0; i < 4; ++i) {
            int e = (i * 256 + tid) * 4;
            int k = e >> 6, nn = e & 63;
            float4 v = *(const float4*)&Wcm[(size_t)k * DM + n0 + nn];
            LT[k][nn] = v.x; LT[k][nn + 1] = v.y; LT[k][nn + 2] = v.z; LT[k][nn + 3] = v.w;
        }
        __syncthreads();
#pragma unroll
        for (int i = 0; i < 4; ++i) {
            int e = (i * 256 + tid) * 4;
            int nn = e >> 6, k = e & 63;
            us4 o;
            o.x = f2b(LT[k][nn]); o.y = f2b(LT[k + 1][nn]);
            o.z = f2b(LT[k + 2][nn]); o.w = f2b(LT[k + 3][nn]);
            *(us4*)&WcT[(size_t)(n0 + nn) * RK + k] = o;
        }
    }
}

// ---------------- main: out = (u @ W_eff) @ W_c_model + D*u ----------------
// 8 waves/block, 16 rows/block. Phase 1: K-split (wave w owns K in [w*256,+256)),
// A-fragments loaded straight from global u (no LDS staging), cross-wave f32
// reduction of t[16][64] in LDS. Phase 2: operand-SWAPPED mfma so each lane
// holds 4 consecutive output columns -> float4 stores + float4 fp32 u reload
// for the D-term (no clobber hack).
__global__ __launch_bounds__(512, 5) void k_main(const float* __restrict__ u,
                                                 const ushort_t* __restrict__ WeffT,
                                                 const ushort_t* __restrict__ WcT,
                                                 const float* __restrict__ Dvec,
                                                 float* __restrict__ out) {
    __shared__ float red[8][64][20];       // [wave][n][r] partial t, 40 KB
    __shared__ ushort_t tsh[16 * 72];      // t bf16, stride 72 (2-way max)

    const int tid = threadIdx.x;
    const int w = tid >> 6;
    const int lane = tid & 63;
    const int m16 = lane & 15;
    const int quad = lane >> 4;
    const size_t row0 = (size_t)blockIdx.x * 16;
    const float* ub = u + row0 * DM;

    // ---- phase 1: partial t over K-slice [w*256, w*256+256) ----
    f32x4 acc0 = {0.f, 0.f, 0.f, 0.f}, acc1 = acc0, acc2 = acc0, acc3 = acc0;
    const float* ap = ub + m16 * DM + w * 256 + quad * 8;
    const ushort_t* bp0 = WeffT + (size_t)m16 * DM + w * 256 + quad * 8;
#pragma unroll 4
    for (int ks = 0; ks < 8; ++ks) {
        const int k0 = ks * 32;
        float4 u0 = *(const float4*)(ap + k0);
        float4 u1 = *(const float4*)(ap + k0 + 4);
        bf16x8 a;
        a[0] = (short)f2b(u0.x); a[1] = (short)f2b(u0.y);
        a[2] = (short)f2b(u0.z); a[3] = (short)f2b(u0.w);
        a[4] = (short)f2b(u1.x); a[5] = (short)f2b(u1.y);
        a[6] = (short)f2b(u1.z); a[7] = (short)f2b(u1.w);
        bf16x8 b0 = *(const bf16x8*)(bp0 + k0);
        bf16x8 b1 = *(const bf16x8*)(bp0 + 16 * DM + k0);
        bf16x8 b2 = *(const bf16x8*)(bp0 + 32 * DM + k0);
        bf16x8 b3 = *(const bf16x8*)(bp0 + 48 * DM + k0);
        acc0 = __builtin_amdgcn_mfma_f32_16x16x32_bf16(a, b0, acc0, 0, 0, 0);
        acc1 = __builtin_amdgcn_mfma_f32_16x16x32_bf16(a, b1, acc1, 0, 0, 0);
        acc2 = __builtin_amdgcn_mfma_f32_16x16x32_bf16(a, b2, acc2, 0, 0, 0);
        acc3 = __builtin_amdgcn_mfma_f32_16x16x32_bf16(a, b3, acc3, 0, 0, 0);
    }
    // D-layout: row(=u-row) = quad*4+i, col(=n) = m16  -> red[w][n][r] contiguous in r
    *(f32x4*)&red[w][ 0 + m16][quad * 4] = acc0;
    *(f32x4*)&red[w][16 + m16][quad * 4] = acc1;
    *(f32x4*)&red[w][32 + m16][quad * 4] = acc2;
    *(f32x4*)&red[w][48 + m16][quad * 4] = acc3;
    __syncthreads();

    // ---- cross-wave reduce: 1024 t-entries / 512 threads = 2 each ----
    {
        const int n = tid >> 3, r2 = (tid & 7) * 2;
        float s0 = 0.f, s1 = 0.f;
#pragma unroll
        for (int ww = 0; ww < 8; ++ww) {
            float2 v = *(const float2*)&red[ww][n][r2];
            s0 += v.x; s1 += v.y;
        }
        tsh[r2 * 72 + n]       = f2b(s0);
        tsh[(r2 + 1) * 72 + n] = f2b(s1);
    }
    __syncthreads();

    // ---- phase 2: wave w owns cols [w*256, +256); swapped operands ----
    bf16x8 ta0 = *(const bf16x8*)&tsh[m16 * 72 + quad * 8];
    bf16x8 ta1 = *(const bf16x8*)&tsh[m16 * 72 + 32 + quad * 8];
    const ushort_t* wcb = WcT + (size_t)(w * 256 + m16) * RK + quad * 8;
    const float* u2 = ub + m16 * DM + w * 256 + quad * 4;
    const float* dp = Dvec + w * 256 + quad * 4;
    float* op = out + (row0 + m16) * DM + w * 256 + quad * 4;
#pragma unroll 2
    for (int nt = 0; nt < 16; ++nt) {
        const ushort_t* bp2 = wcb + nt * 16 * RK;
        bf16x8 wb0 = *(const bf16x8*)(bp2);
        bf16x8 wb1 = *(const bf16x8*)(bp2 + 32);
        f32x4 o = {0.f, 0.f, 0.f, 0.f};
        // A = WcT rows (out-cols), B = t rows (out-rows):
        // lane gets out[row0+m16][w*256 + nt*16 + quad*4 + i]  -> float4 store
        o = __builtin_amdgcn_mfma_f32_16x16x32_bf16(wb0, ta0, o, 0, 0, 0);
        o = __builtin_amdgcn_mfma_f32_16x16x32_bf16(wb1, ta1, o, 0, 0, 0);
        float4 uv = *(const float4*)(u2 + nt * 16);
        float4 dv = *(const float4*)(dp + nt * 16);
        f32x4 st;
        st.x = o[0] + dv.x * uv.x;
        st.y = o[1] + dv.y * uv.y;
        st.z = o[2] + dv.z * uv.z;
        st.w = o[3] + dv.w * uv.w;
        __builtin_nontemporal_store(st, (f32x4*)(op + nt * 16));
    }
}

extern "C" void kernel_launch(void* const* d_in, const int* in_sizes, int n_in,
                              void* d_out, int out_size, void* d_ws, size_t ws_size,
                              hipStream_t stream) {
    (void)in_sizes; (void)n_in; (void)out_size; (void)ws_size;
    const float* u   = (const float*)d_in[0];
    const float* Af  = (const float*)d_in[1];
    const float* Wbr = (const float*)d_in[2];
    const float* Wbs = (const float*)d_in[3];
    const float* Wcr = (const float*)d_in[4];
    const float* Wcm = (const float*)d_in[5];
    const float* Dv  = (const float*)d_in[6];
    float* out = (float*)d_out;

    char* ws = (char*)d_ws;
    float*    Mmid  = (float*)(ws + 0);            // 64*64*4   = 16384
    ushort_t* WeffT = (ushort_t*)(ws + 16384);     // 64*2048*2 = 262144
    ushort_t* WcT   = (ushort_t*)(ws + 278528);    // 2048*64*2 = 262144

    k_p1<<<16, 256, 0, stream>>>(Wbs, Af, Wcr, Mmid);
    k_p2<<<64, 256, 0, stream>>>(Wbr, Mmid, Wcm, WeffT, WcT);
    k_main<<<1024, 512, 0, stream>>>(u, WeffT, WcT, Dv, out);
}

// Round 3
// 323.120 us; speedup vs baseline: 1.0383x; 1.0126x over previous
//
#include <hip/hip_runtime.h>

typedef unsigned short ushort_t;
typedef __attribute__((ext_vector_type(8))) short bf16x8;     // 8 bf16 (4 VGPRs)
typedef __attribute__((ext_vector_type(4))) float f32x4;
typedef __attribute__((ext_vector_type(4))) unsigned short us4;

#define DM 2048
#define RK 64

__device__ __forceinline__ ushort_t f2b(float f) {
    union { float f; unsigned u; } x; x.f = f;
    unsigned r = x.u + 0x7fff + ((x.u >> 16) & 1);   // RNE
    return (ushort_t)(r >> 16);
}

// ---------------- P1: Mmid[64][64] = butterfly(Wbs) @ Wcr ----------------
__global__ void k_p1(const float* __restrict__ Wbs, const float* __restrict__ Af,
                     const float* __restrict__ Wcr, float* __restrict__ Mmid) {
    __shared__ float X[64 * 256];          // 64 KB, becomes T1
    const int tid = threadIdx.x;
#pragma unroll
    for (int i = 0; i < 16; ++i) {
        int e = (i * 256 + tid) * 4;
        *(float4*)&X[e] = *(const float4*)&Wbs[e];
    }
    __syncthreads();
#pragma unroll
    for (int l = 0; l < 8; ++l) {
        const int bit = 1 << (7 - l);
        const float a00 = Af[l * 4 + 0], a01 = Af[l * 4 + 1];
        const float a10 = Af[l * 4 + 2], a11 = Af[l * 4 + 3];
#pragma unroll 4
        for (int p = 0; p < 32; ++p) {
            int pid = p * 256 + tid;
            int row = pid >> 7;
            int off = pid & 127;
            int lo = off & (bit - 1);
            int n0 = ((off ^ lo) << 1) | lo;
            int n1 = n0 | bit;
            float x0 = X[row * 256 + n0], x1 = X[row * 256 + n1];
            X[row * 256 + n0] = x0 * a00 + x1 * a10;
            X[row * 256 + n1] = x0 * a01 + x1 * a11;
        }
        __syncthreads();
    }
    int g = blockIdx.x * 256 + tid;
    int r1 = g >> 6, r2 = g & 63;
    float s = 0.f;
#pragma unroll 8
    for (int n = 0; n < 256; ++n) s += X[r1 * 256 + n] * Wcr[n * 64 + r2];
    Mmid[g] = s;
}

// ---------------- P2: WeffT[64][2048] = (Wbr @ Mmid)^T, WcT[2048][64] = Wcm^T ----
__global__ void k_p2(const float* __restrict__ Wbr, const float* __restrict__ Mmid,
                     const float* __restrict__ Wcm,
                     ushort_t* __restrict__ WeffT, ushort_t* __restrict__ WcT) {
    const int b = blockIdx.x, tid = threadIdx.x;
    if (b < 32) {
        __shared__ float LW[64][65];
        __shared__ float LM[64 * 64];
#pragma unroll
        for (int i = 0; i < 4; ++i) {
            int e = (i * 256 + tid) * 4;
            int kk = e >> 6, r = e & 63;
            float4 v = *(const float4*)&Wbr[(size_t)b * 4096 + e];
            LW[kk][r] = v.x; LW[kk][r + 1] = v.y; LW[kk][r + 2] = v.z; LW[kk][r + 3] = v.w;
        }
#pragma unroll
        for (int i = 0; i < 4; ++i) {
            int e = (i * 256 + tid) * 4;
            *(float4*)&LM[e] = *(const float4*)&Mmid[e];
        }
        __syncthreads();
        int kk = tid & 63, n0 = (tid >> 6) * 16;
        float acc[16];
#pragma unroll
        for (int j = 0; j < 16; ++j) acc[j] = 0.f;
        for (int r = 0; r < 64; ++r) {
            float wv = LW[kk][r];
            const float* mrow = &LM[r * 64 + n0];
            float4 m0 = *(const float4*)(mrow);
            float4 m1 = *(const float4*)(mrow + 4);
            float4 m2 = *(const float4*)(mrow + 8);
            float4 m3 = *(const float4*)(mrow + 12);
            acc[0] += wv * m0.x; acc[1] += wv * m0.y; acc[2] += wv * m0.z; acc[3] += wv * m0.w;
            acc[4] += wv * m1.x; acc[5] += wv * m1.y; acc[6] += wv * m1.z; acc[7] += wv * m1.w;
            acc[8] += wv * m2.x; acc[9] += wv * m2.y; acc[10] += wv * m2.z; acc[11] += wv * m2.w;
            acc[12] += wv * m3.x; acc[13] += wv * m3.y; acc[14] += wv * m3.z; acc[15] += wv * m3.w;
        }
#pragma unroll
        for (int j = 0; j < 16; ++j)
            WeffT[(size_t)(n0 + j) * DM + b * 64 + kk] = f2b(acc[j]);
    } else {
        __shared__ float LT[64][65];
        const int n0 = (b - 32) * 64;
#pragma unroll
        for (int i = 0; i < 4; ++i) {
            int e = (i * 256 + tid) * 4;
            int k = e >> 6, nn = e & 63;
            float4 v = *(const float4*)&Wcm[(size_t)k * DM + n0 + nn];
            LT[k][nn] = v.x; LT[k][nn + 1] = v.y; LT[k][nn + 2] = v.z; LT[k][nn + 3] = v.w;
        }
        __syncthreads();
#pragma unroll
        for (int i = 0; i < 4; ++i) {
            int e = (i * 256 + tid) * 4;
            int nn = e >> 6, k = e & 63;
            us4 o;
            o.x = f2b(LT[k][nn]); o.y = f2b(LT[k + 1][nn]);
            o.z = f2b(LT[k + 2][nn]); o.w = f2b(LT[k + 3][nn]);
            *(us4*)&WcT[(size_t)(n0 + nn) * RK + k] = o;
        }
    }
}

// ---------------- A: t[16384][64] = u @ W_eff (bf16 out) ----------------
// 1024 blocks x 128 threads (2 waves). Each block owns one 16-row tile;
// the 2 waves split K (1024 each), one light barrier + 8KB LDS reduce.
// No phase lockstep across waves beyond a single tiny barrier.
__global__ __launch_bounds__(128) void k_a(const float* __restrict__ u,
                                           const ushort_t* __restrict__ WeffT,
                                           ushort_t* __restrict__ tg) {
    __shared__ float red[2][16][68];       // stride 68: 2-way max conflict
    const int tid = threadIdx.x;
    const int w = tid >> 6;                // K-slice 0/1
    const int lane = tid & 63;
    const int m16 = lane & 15;
    const int quad = lane >> 4;
    const size_t row0 = (size_t)blockIdx.x * 16;
    const float* ap = u + (row0 + m16) * DM + w * 1024 + quad * 8;
    const ushort_t* bp0 = WeffT + (size_t)m16 * DM + w * 1024 + quad * 8;

    f32x4 acc0 = {0.f, 0.f, 0.f, 0.f}, acc1 = acc0, acc2 = acc0, acc3 = acc0;
#pragma unroll 4
    for (int kk = 0; kk < 32; ++kk) {
        const int k0 = kk * 32;
        float4 u0 = *(const float4*)(ap + k0);
        float4 u1 = *(const float4*)(ap + k0 + 4);
        bf16x8 a;
        a[0] = (short)f2b(u0.x); a[1] = (short)f2b(u0.y);
        a[2] = (short)f2b(u0.z); a[3] = (short)f2b(u0.w);
        a[4] = (short)f2b(u1.x); a[5] = (short)f2b(u1.y);
        a[6] = (short)f2b(u1.z); a[7] = (short)f2b(u1.w);
        bf16x8 b0 = *(const bf16x8*)(bp0 + k0);
        bf16x8 b1 = *(const bf16x8*)(bp0 + 16 * DM + k0);
        bf16x8 b2 = *(const bf16x8*)(bp0 + 32 * DM + k0);
        bf16x8 b3 = *(const bf16x8*)(bp0 + 48 * DM + k0);
        acc0 = __builtin_amdgcn_mfma_f32_16x16x32_bf16(a, b0, acc0, 0, 0, 0);
        acc1 = __builtin_amdgcn_mfma_f32_16x16x32_bf16(a, b1, acc1, 0, 0, 0);
        acc2 = __builtin_amdgcn_mfma_f32_16x16x32_bf16(a, b2, acc2, 0, 0, 0);
        acc3 = __builtin_amdgcn_mfma_f32_16x16x32_bf16(a, b3, acc3, 0, 0, 0);
    }
    // C layout: row = quad*4+i, col(n) = 16*j + m16
#pragma unroll
    for (int i = 0; i < 4; ++i) {
        red[w][quad * 4 + i][ 0 + m16] = acc0[i];
        red[w][quad * 4 + i][16 + m16] = acc1[i];
        red[w][quad * 4 + i][32 + m16] = acc2[i];
        red[w][quad * 4 + i][48 + m16] = acc3[i];
    }
    __syncthreads();

    // 1024 t-entries / 128 threads = 8 each (contiguous), bf16 out
    {
        const int row = tid >> 3, c0 = (tid & 7) * 8;
        float4 p0 = *(const float4*)&red[0][row][c0];
        float4 p1 = *(const float4*)&red[0][row][c0 + 4];
        float4 q0 = *(const float4*)&red[1][row][c0];
        float4 q1 = *(const float4*)&red[1][row][c0 + 4];
        us4 o0, o1;
        o0.x = f2b(p0.x + q0.x); o0.y = f2b(p0.y + q0.y);
        o0.z = f2b(p0.z + q0.z); o0.w = f2b(p0.w + q0.w);
        o1.x = f2b(p1.x + q1.x); o1.y = f2b(p1.y + q1.y);
        o1.z = f2b(p1.z + q1.z); o1.w = f2b(p1.w + q1.w);
        ushort_t* tp = tg + (size_t)blockIdx.x * 1024 + tid * 8;
        *(us4*)tp = o0;
        *(us4*)(tp + 4) = o1;
    }
}

// ---------------- B: out = t @ W_c_model + D*u ----------------
// 1024 blocks x 256 threads (4 waves), zero LDS, zero barriers.
// Wave w owns out cols [w*512, +512) of its 16-row tile.
__global__ __launch_bounds__(256) void k_b(const ushort_t* __restrict__ tg,
                                           const float* __restrict__ u,
                                           const ushort_t* __restrict__ WcT,
                                           const float* __restrict__ Dvec,
                                           float* __restrict__ out) {
    const int tid = threadIdx.x;
    const int w = tid >> 6;
    const int lane = tid & 63;
    const int m16 = lane & 15;
    const int quad = lane >> 4;
    const size_t row0 = (size_t)blockIdx.x * 16;
    const ushort_t* tb = tg + (size_t)blockIdx.x * 1024;

    bf16x8 ta0 = *(const bf16x8*)&tb[m16 * 64 + quad * 8];
    bf16x8 ta1 = *(const bf16x8*)&tb[m16 * 64 + 32 + quad * 8];
    const ushort_t* wcb = WcT + (size_t)(w * 512 + m16) * RK + quad * 8;
    const float* u2 = u + (row0 + m16) * DM + w * 512 + quad * 4;
    const float* dp = Dvec + w * 512 + quad * 4;
    float* op = out + (row0 + m16) * DM + w * 512 + quad * 4;
#pragma unroll 2
    for (int nt = 0; nt < 32; ++nt) {
        const ushort_t* bp2 = wcb + nt * 16 * RK;
        bf16x8 wb0 = *(const bf16x8*)(bp2);
        bf16x8 wb1 = *(const bf16x8*)(bp2 + 32);
        f32x4 o = {0.f, 0.f, 0.f, 0.f};
        // A = WcT rows (out-cols), B = t rows (out-rows):
        // lane gets out[row0+m16][w*512 + nt*16 + quad*4 + i] -> float4 store
        o = __builtin_amdgcn_mfma_f32_16x16x32_bf16(wb0, ta0, o, 0, 0, 0);
        o = __builtin_amdgcn_mfma_f32_16x16x32_bf16(wb1, ta1, o, 0, 0, 0);
        float4 uv = *(const float4*)(u2 + nt * 16);
        float4 dv = *(const float4*)(dp + nt * 16);
        f32x4 st;
        st.x = o[0] + dv.x * uv.x;
        st.y = o[1] + dv.y * uv.y;
        st.z = o[2] + dv.z * uv.z;
        st.w = o[3] + dv.w * uv.w;
        __builtin_nontemporal_store(st, (f32x4*)(op + nt * 16));
    }
}

extern "C" void kernel_launch(void* const* d_in, const int* in_sizes, int n_in,
                              void* d_out, int out_size, void* d_ws, size_t ws_size,
                              hipStream_t stream) {
    (void)in_sizes; (void)n_in; (void)out_size; (void)ws_size;
    const float* u   = (const float*)d_in[0];
    const float* Af  = (const float*)d_in[1];
    const float* Wbr = (const float*)d_in[2];
    const float* Wbs = (const float*)d_in[3];
    const float* Wcr = (const float*)d_in[4];
    const float* Wcm = (const float*)d_in[5];
    const float* Dv  = (const float*)d_in[6];
    float* out = (float*)d_out;

    char* ws = (char*)d_ws;
    float*    Mmid  = (float*)(ws + 0);            // 64*64*4    =   16384
    ushort_t* WeffT = (ushort_t*)(ws + 16384);     // 64*2048*2  =  262144
    ushort_t* WcT   = (ushort_t*)(ws + 278528);    // 2048*64*2  =  262144
    ushort_t* tg    = (ushort_t*)(ws + 540672);    // 16384*64*2 = 2097152

    k_p1<<<16, 256, 0, stream>>>(Wbs, Af, Wcr, Mmid);
    k_p2<<<64, 256, 0, stream>>>(Wbr, Mmid, Wcm, WeffT, WcT);
    k_a <<<1024, 128, 0, stream>>>(u, WeffT, tg);
    k_b <<<1024, 256, 0, stream>>>(tg, u, WcT, Dv, out);
}